// Round 4
// baseline (608.787 us; speedup 1.0000x reference)
//
#include <hip/hip_runtime.h>

// GIN: 3 layers of {agg = scatter_sum(h[src] -> dst); h = relu(((1+eps)h + agg) @ W + b)}
// then per-graph segment-sum readout (graph_ids sorted) -> 2-layer MLP.
//
// R4: bf16 storage for x-cast and H (f32 accumulation everywhere).
//     Row = 128B; gather fetch per XCD halves; L2 hit rate ~doubles.
// R3: 3-kernel parallel scan. R2: MLP-gather re-layout (4 edges/wave-load).

#define SPLIT 16

typedef unsigned short ushort_t;

__device__ __forceinline__ ushort_t f2bf(float f) {
    unsigned int u = __float_as_uint(f);
    unsigned int r = (u + 0x7fffu + ((u >> 16) & 1u)) >> 16;   // RNE
    return (ushort_t)r;
}
__device__ __forceinline__ float bf2f_lo(unsigned int v) {
    return __uint_as_float(v << 16);
}
__device__ __forceinline__ float bf2f_hi(unsigned int v) {
    return __uint_as_float(v & 0xffff0000u);
}

__global__ void cast_kernel(const float* __restrict__ x, ushort_t* __restrict__ xb, int n4) {
    int i = blockIdx.x * blockDim.x + threadIdx.x;
    if (i < n4) {
        float4 v = ((const float4*)x)[i];
        uint2 p;
        p.x = (unsigned int)f2bf(v.x) | ((unsigned int)f2bf(v.y) << 16);
        p.y = (unsigned int)f2bf(v.z) | ((unsigned int)f2bf(v.w) << 16);
        ((uint2*)xb)[i] = p;
    }
}

__global__ void hist_kernel(const int* __restrict__ dst, int* __restrict__ deg, int E) {
    int i = blockIdx.x * blockDim.x + threadIdx.x;
    if (i < E) atomicAdd(&deg[dst[i]], 1);
}

// --- 3-phase parallel scan over deg[N] -> offsets[N+1] ---
__global__ __launch_bounds__(256) void scan_part_kernel(const int* __restrict__ deg,
                                                        int* __restrict__ bsum, int N) {
    __shared__ int sh[256];
    int t = threadIdx.x;
    int i = (blockIdx.x * 256 + t) * 2;
    int s = 0;
    if (i < N) s += deg[i];
    if (i + 1 < N) s += deg[i + 1];
    sh[t] = s;
    __syncthreads();
    for (int off = 128; off > 0; off >>= 1) {
        if (t < off) sh[t] += sh[t + off];
        __syncthreads();
    }
    if (t == 0) bsum[blockIdx.x] = sh[0];
}

__global__ __launch_bounds__(256) void scan_mid_kernel(const int* __restrict__ bsum,
                                                       int* __restrict__ boff, int nb) {
    __shared__ int sh[256];
    int t = threadIdx.x;
    int v = (t < nb) ? bsum[t] : 0;
    sh[t] = v;
    __syncthreads();
    for (int off = 1; off < 256; off <<= 1) {
        int u = (t >= off) ? sh[t - off] : 0;
        __syncthreads();
        sh[t] += u;
        __syncthreads();
    }
    if (t < nb) boff[t] = sh[t] - v;
}

__global__ __launch_bounds__(256) void scan_final_kernel(const int* __restrict__ deg,
                                                         const int* __restrict__ boff,
                                                         int* __restrict__ offsets,
                                                         int N, int E) {
    __shared__ int sh[256];
    int t = threadIdx.x;
    int i = (blockIdx.x * 256 + t) * 2;
    int d0 = (i < N) ? deg[i] : 0;
    int d1 = (i + 1 < N) ? deg[i + 1] : 0;
    int s = d0 + d1;
    sh[t] = s;
    __syncthreads();
    for (int off = 1; off < 256; off <<= 1) {
        int u = (t >= off) ? sh[t - off] : 0;
        __syncthreads();
        sh[t] += u;
        __syncthreads();
    }
    int pre = boff[blockIdx.x] + sh[t] - s;
    if (i < N) offsets[i] = pre;
    if (i + 1 < N) offsets[i + 1] = pre + d0;
    if (blockIdx.x == 0 && t == 0) offsets[N] = E;
}

__global__ void fill_kernel(const int* __restrict__ src, const int* __restrict__ dst,
                            const int* __restrict__ offsets, int* __restrict__ cnt,
                            int* __restrict__ csr, int E) {
    int i = blockIdx.x * blockDim.x + threadIdx.x;
    if (i < E) {
        int d = dst[i];
        int pos = offsets[d] + atomicAdd(&cnt[d], 1);
        csr[pos] = src[i];
    }
}

// One wave per node. lane = g*16+sl. Group g handles edges e0+g, e0+g+4, ...
// bf16 rows: 16 lanes x uint2 (4 bf16) = 128B row. f32 accumulate.
__global__ __launch_bounds__(256) void gin_layer_kernel(
        const ushort_t* __restrict__ hin, ushort_t* __restrict__ hout,
        const int* __restrict__ offsets, const int* __restrict__ csr,
        const float* __restrict__ gin_W, const float* __restrict__ gin_b,
        const float* __restrict__ eps_arr, int layer, int N) {
    __shared__ float Ws[64 * 64];
    __shared__ float bs[64];
    const float* Wl = gin_W + layer * 4096;
    for (int i = threadIdx.x; i < 1024; i += 256)
        ((float4*)Ws)[i] = ((const float4*)Wl)[i];
    if (threadIdx.x < 64) bs[threadIdx.x] = gin_b[layer * 64 + threadIdx.x];
    float eps1 = 1.0f + eps_arr[layer];
    __syncthreads();

    int lane = threadIdx.x & 63;
    int wave = threadIdx.x >> 6;
    int n = blockIdx.x * 4 + wave;
    if (n >= N) return;

    int g  = lane >> 4;    // edge group 0..3
    int sl = lane & 15;    // uint2 slot within row (dims 4sl..4sl+3)

    int e0 = offsets[n], e1 = offsets[n + 1];
    float ax = 0.f, ay = 0.f, az = 0.f, aw = 0.f;

    int e = e0 + g;
    for (; e + 4 < e1; e += 8) {
        int s0 = csr[e];
        int s1 = csr[e + 4];
        uint2 v0 = ((const uint2*)(hin + (size_t)s0 * 64))[sl];
        uint2 v1 = ((const uint2*)(hin + (size_t)s1 * 64))[sl];
        ax += bf2f_lo(v0.x); ay += bf2f_hi(v0.x); az += bf2f_lo(v0.y); aw += bf2f_hi(v0.y);
        ax += bf2f_lo(v1.x); ay += bf2f_hi(v1.x); az += bf2f_lo(v1.y); aw += bf2f_hi(v1.y);
    }
    if (e < e1) {
        int s0 = csr[e];
        uint2 v0 = ((const uint2*)(hin + (size_t)s0 * 64))[sl];
        ax += bf2f_lo(v0.x); ay += bf2f_hi(v0.x); az += bf2f_lo(v0.y); aw += bf2f_hi(v0.y);
    }

    ax += __shfl_xor(ax, 16, 64); ax += __shfl_xor(ax, 32, 64);
    ay += __shfl_xor(ay, 16, 64); ay += __shfl_xor(ay, 32, 64);
    az += __shfl_xor(az, 16, 64); az += __shfl_xor(az, 32, 64);
    aw += __shfl_xor(aw, 16, 64); aw += __shfl_xor(aw, 32, 64);

    uint2 self = ((const uint2*)(hin + (size_t)n * 64))[sl];
    ax = fmaf(eps1, bf2f_lo(self.x), ax);
    ay = fmaf(eps1, bf2f_hi(self.x), ay);
    az = fmaf(eps1, bf2f_lo(self.y), az);
    aw = fmaf(eps1, bf2f_hi(self.y), aw);

    float out = bs[lane];
    #pragma unroll
    for (int k = 0; k < 16; ++k) {
        float b0 = __shfl(ax, k, 64);
        float b1 = __shfl(ay, k, 64);
        float b2 = __shfl(az, k, 64);
        float b3 = __shfl(aw, k, 64);
        out = fmaf(b0, Ws[(4 * k + 0) * 64 + lane], out);
        out = fmaf(b1, Ws[(4 * k + 1) * 64 + lane], out);
        out = fmaf(b2, Ws[(4 * k + 2) * 64 + lane], out);
        out = fmaf(b3, Ws[(4 * k + 3) * 64 + lane], out);
    }
    out = fmaxf(out, 0.0f);
    hout[(size_t)n * 64 + lane] = f2bf(out);
}

// 256 graphs x SPLIT splits; 192 threads (t = l*64+d); bf16 H, f32 accumulate.
__global__ __launch_bounds__(192) void readout_kernel(
        const ushort_t* __restrict__ H, const int* __restrict__ gids,
        float* __restrict__ g, int N) {
    int graph = blockIdx.x / SPLIT;
    int sp    = blockIdx.x % SPLIT;
    int lo = 0, hi = N;
    while (lo < hi) { int mid = (lo + hi) >> 1; if (gids[mid] < graph) lo = mid + 1; else hi = mid; }
    int start = lo;
    int lo2 = start, hi2 = N;
    while (lo2 < hi2) { int mid = (lo2 + hi2) >> 1; if (gids[mid] < graph + 1) lo2 = mid + 1; else hi2 = mid; }
    int end = lo2;
    int cnt = end - start;
    if (cnt <= 0) return;
    int per = (cnt + SPLIT - 1) / SPLIT;
    int cs = start + sp * per;
    int ce = min(cs + per, end);
    if (cs >= ce) return;

    int t = threadIdx.x;            // 0..191
    int l = t >> 6, d = t & 63;
    const ushort_t* Hl = H + (size_t)l * N * 64;
    float acc = 0.0f;
    for (int n = cs; n < ce; ++n)
        acc += bf2f_lo((unsigned int)Hl[(size_t)n * 64 + d]);
    atomicAdd(&g[graph * 192 + t], acc);
}

__global__ __launch_bounds__(192) void mlp_kernel(
        const float* __restrict__ g,
        const float* __restrict__ W1, const float* __restrict__ b1,
        const float* __restrict__ W2, const float* __restrict__ b2,
        float* __restrict__ out) {
    __shared__ float gr[192];
    __shared__ float hid[128];
    int graph = blockIdx.x;
    int t = threadIdx.x;
    gr[t] = g[graph * 192 + t];
    __syncthreads();
    if (t < 128) {
        float a = b1[t];
        for (int k = 0; k < 192; ++k) a = fmaf(gr[k], W1[k * 128 + t], a);
        hid[t] = fmaxf(a, 0.0f);
    }
    __syncthreads();
    if (t < 32) {
        float a = b2[t];
        for (int k = 0; k < 128; ++k) a = fmaf(hid[k], W2[k * 32 + t], a);
        out[graph * 32 + t] = a;
    }
}

extern "C" void kernel_launch(void* const* d_in, const int* in_sizes, int n_in,
                              void* d_out, int out_size, void* d_ws, size_t ws_size,
                              hipStream_t stream) {
    const float* x     = (const float*)d_in[0];
    const float* gin_W = (const float*)d_in[1];
    const float* gin_b = (const float*)d_in[2];
    const float* eps   = (const float*)d_in[3];
    const float* r_W1  = (const float*)d_in[4];
    const float* r_b1  = (const float*)d_in[5];
    const float* r_W2  = (const float*)d_in[6];
    const float* r_b2  = (const float*)d_in[7];
    const int*   src   = (const int*)d_in[8];
    const int*   dst   = (const int*)d_in[9];
    const int*   gids  = (const int*)d_in[10];

    int N = in_sizes[0] / 64;       // 100000
    int E = in_sizes[8];            // 1200000
    int B = out_size / 32;          // 256

    // workspace layout (4B words):
    //   deg[N] | cnt[N] | g[B*192]            <- zeroed
    //   offsets[N+1] | csr[E] | bsum | boff | pad->64B | xb[N*64 bf16] | H[3*N*64 bf16]
    int nb_scan = (N + 511) / 512;
    int* ws       = (int*)d_ws;
    int* deg      = ws;
    int* cnt      = ws + N;
    float* g      = (float*)(ws + 2 * (size_t)N);
    int* offsets  = ws + 2 * (size_t)N + B * 192;
    int* csr      = offsets + (N + 1);
    int* bsum     = csr + E;
    int* boff     = bsum + nb_scan;
    size_t w      = (size_t)(boff + nb_scan - ws);
    w = (w + 15) & ~(size_t)15;     // 64B align
    ushort_t* xb  = (ushort_t*)(ws + w);
    ushort_t* H   = xb + (size_t)N * 64;

    size_t zero_bytes = (2 * (size_t)N + (size_t)B * 192) * sizeof(int);
    hipMemsetAsync(d_ws, 0, zero_bytes, stream);

    int eb = (E + 255) / 256;
    cast_kernel<<<(N * 64 / 4 + 255) / 256, 256, 0, stream>>>(x, xb, N * 64 / 4);
    hist_kernel<<<eb, 256, 0, stream>>>(dst, deg, E);
    scan_part_kernel<<<nb_scan, 256, 0, stream>>>(deg, bsum, N);
    scan_mid_kernel<<<1, 256, 0, stream>>>(bsum, boff, nb_scan);
    scan_final_kernel<<<nb_scan, 256, 0, stream>>>(deg, boff, offsets, N, E);
    fill_kernel<<<eb, 256, 0, stream>>>(src, dst, offsets, cnt, csr, E);

    int nbk = (N + 3) / 4;
    ushort_t* H0 = H;
    ushort_t* H1 = H + (size_t)N * 64;
    ushort_t* H2 = H + 2 * (size_t)N * 64;
    gin_layer_kernel<<<nbk, 256, 0, stream>>>(xb, H0, offsets, csr, gin_W, gin_b, eps, 0, N);
    gin_layer_kernel<<<nbk, 256, 0, stream>>>(H0, H1, offsets, csr, gin_W, gin_b, eps, 1, N);
    gin_layer_kernel<<<nbk, 256, 0, stream>>>(H1, H2, offsets, csr, gin_W, gin_b, eps, 2, N);

    readout_kernel<<<B * SPLIT, 192, 0, stream>>>(H, gids, g, N);
    mlp_kernel<<<B, 192, 0, stream>>>(g, r_W1, r_b1, r_W2, r_b2, (float*)d_out);
}

// Round 5
// 451.108 us; speedup vs baseline: 1.3495x; 1.3495x over previous
//
#include <hip/hip_runtime.h>

// GIN: 3 layers of {agg = scatter_sum(h[src] -> dst); h = relu(((1+eps)h + agg) @ W + b)}
// then per-graph segment-sum readout (graph_ids sorted) -> 2-layer MLP.
//
// R5: split each layer into agg (gather, DS-free) + MFMA GEMM (LDS-free).
//     R4 post-mortem: DS pipe was ~100% busy (64 ds_read + 72 shfl per node);
//     FETCH halving gave no speedup. GEMM uses bf16 hi/lo split (3 MFMAs) for
//     ~f32 precision; agg stored f32.
// R4: bf16 H storage. R3: parallel scan. R2: gather MLP re-layout.

#define SPLIT 16

typedef unsigned short ushort_t;
typedef __bf16 v8bf __attribute__((ext_vector_type(8)));
typedef float v4f __attribute__((ext_vector_type(4)));

__device__ __forceinline__ ushort_t f2bf(float f) {
    unsigned int u = __float_as_uint(f);
    unsigned int r = (u + 0x7fffu + ((u >> 16) & 1u)) >> 16;   // RNE
    return (ushort_t)r;
}
__device__ __forceinline__ float bf2f_lo(unsigned int v) {
    return __uint_as_float(v << 16);
}
__device__ __forceinline__ float bf2f_hi(unsigned int v) {
    return __uint_as_float(v & 0xffff0000u);
}

__global__ void cast_kernel(const float* __restrict__ x, ushort_t* __restrict__ xb, int n4) {
    int i = blockIdx.x * blockDim.x + threadIdx.x;
    if (i < n4) {
        float4 v = ((const float4*)x)[i];
        uint2 p;
        p.x = (unsigned int)f2bf(v.x) | ((unsigned int)f2bf(v.y) << 16);
        p.y = (unsigned int)f2bf(v.z) | ((unsigned int)f2bf(v.w) << 16);
        ((uint2*)xb)[i] = p;
    }
}

// W[l][k][n] f32 -> Wt_hi/Wt_lo[l][n][k] bf16 (transposed, hi+lo split)
__global__ void prep_w_kernel(const float* __restrict__ W,
                              ushort_t* __restrict__ whi, ushort_t* __restrict__ wlo,
                              int total) {
    int i = blockIdx.x * blockDim.x + threadIdx.x;
    if (i >= total) return;
    int l = i >> 12, r = i & 4095;
    int n = r >> 6, k = r & 63;
    float w = W[l * 4096 + k * 64 + n];
    __bf16 h = (__bf16)w;
    float rem = w - (float)h;
    __bf16 lo = (__bf16)rem;
    whi[i] = __builtin_bit_cast(ushort_t, h);
    wlo[i] = __builtin_bit_cast(ushort_t, lo);
}

__global__ void hist_kernel(const int* __restrict__ dst, int* __restrict__ deg, int E) {
    int i = blockIdx.x * blockDim.x + threadIdx.x;
    if (i < E) atomicAdd(&deg[dst[i]], 1);
}

// --- 3-phase parallel scan over deg[N] -> offsets[N+1] ---
__global__ __launch_bounds__(256) void scan_part_kernel(const int* __restrict__ deg,
                                                        int* __restrict__ bsum, int N) {
    __shared__ int sh[256];
    int t = threadIdx.x;
    int i = (blockIdx.x * 256 + t) * 2;
    int s = 0;
    if (i < N) s += deg[i];
    if (i + 1 < N) s += deg[i + 1];
    sh[t] = s;
    __syncthreads();
    for (int off = 128; off > 0; off >>= 1) {
        if (t < off) sh[t] += sh[t + off];
        __syncthreads();
    }
    if (t == 0) bsum[blockIdx.x] = sh[0];
}

__global__ __launch_bounds__(256) void scan_mid_kernel(const int* __restrict__ bsum,
                                                       int* __restrict__ boff, int nb) {
    __shared__ int sh[256];
    int t = threadIdx.x;
    int v = (t < nb) ? bsum[t] : 0;
    sh[t] = v;
    __syncthreads();
    for (int off = 1; off < 256; off <<= 1) {
        int u = (t >= off) ? sh[t - off] : 0;
        __syncthreads();
        sh[t] += u;
        __syncthreads();
    }
    if (t < nb) boff[t] = sh[t] - v;
}

__global__ __launch_bounds__(256) void scan_final_kernel(const int* __restrict__ deg,
                                                         const int* __restrict__ boff,
                                                         int* __restrict__ offsets,
                                                         int N, int E) {
    __shared__ int sh[256];
    int t = threadIdx.x;
    int i = (blockIdx.x * 256 + t) * 2;
    int d0 = (i < N) ? deg[i] : 0;
    int d1 = (i + 1 < N) ? deg[i + 1] : 0;
    int s = d0 + d1;
    sh[t] = s;
    __syncthreads();
    for (int off = 1; off < 256; off <<= 1) {
        int u = (t >= off) ? sh[t - off] : 0;
        __syncthreads();
        sh[t] += u;
        __syncthreads();
    }
    int pre = boff[blockIdx.x] + sh[t] - s;
    if (i < N) offsets[i] = pre;
    if (i + 1 < N) offsets[i + 1] = pre + d0;
    if (blockIdx.x == 0 && t == 0) offsets[N] = E;
}

__global__ void fill_kernel(const int* __restrict__ src, const int* __restrict__ dst,
                            const int* __restrict__ offsets, int* __restrict__ cnt,
                            int* __restrict__ csr, int E) {
    int i = blockIdx.x * blockDim.x + threadIdx.x;
    if (i < E) {
        int d = dst[i];
        int pos = offsets[d] + atomicAdd(&cnt[d], 1);
        csr[pos] = src[i];
    }
}

// One wave per node. lane = g*16+sl. Group g handles edges e0+g, e0+g+4, ...
// bf16 rows in, f32 agg rows out: agg[n] = (1+eps)*h[n] + sum_neighbors h[s].
__global__ __launch_bounds__(256) void agg_kernel(
        const ushort_t* __restrict__ hin, float* __restrict__ agg,
        const int* __restrict__ offsets, const int* __restrict__ csr,
        const float* __restrict__ eps_arr, int layer, int N) {
    int lane = threadIdx.x & 63;
    int wave = threadIdx.x >> 6;
    int n = blockIdx.x * 4 + wave;
    if (n >= N) return;
    float eps1 = 1.0f + eps_arr[layer];

    int g  = lane >> 4;    // edge group 0..3
    int sl = lane & 15;    // uint2 slot within row (dims 4sl..4sl+3)

    int e0 = offsets[n], e1 = offsets[n + 1];
    float ax = 0.f, ay = 0.f, az = 0.f, aw = 0.f;

    int e = e0 + g;
    for (; e + 4 < e1; e += 8) {
        int s0 = csr[e];
        int s1 = csr[e + 4];
        uint2 v0 = ((const uint2*)(hin + (size_t)s0 * 64))[sl];
        uint2 v1 = ((const uint2*)(hin + (size_t)s1 * 64))[sl];
        ax += bf2f_lo(v0.x); ay += bf2f_hi(v0.x); az += bf2f_lo(v0.y); aw += bf2f_hi(v0.y);
        ax += bf2f_lo(v1.x); ay += bf2f_hi(v1.x); az += bf2f_lo(v1.y); aw += bf2f_hi(v1.y);
    }
    if (e < e1) {
        int s0 = csr[e];
        uint2 v0 = ((const uint2*)(hin + (size_t)s0 * 64))[sl];
        ax += bf2f_lo(v0.x); ay += bf2f_hi(v0.x); az += bf2f_lo(v0.y); aw += bf2f_hi(v0.y);
    }

    ax += __shfl_xor(ax, 16, 64); ax += __shfl_xor(ax, 32, 64);
    ay += __shfl_xor(ay, 16, 64); ay += __shfl_xor(ay, 32, 64);
    az += __shfl_xor(az, 16, 64); az += __shfl_xor(az, 32, 64);
    aw += __shfl_xor(aw, 16, 64); aw += __shfl_xor(aw, 32, 64);

    uint2 self = ((const uint2*)(hin + (size_t)n * 64))[sl];
    ax = fmaf(eps1, bf2f_lo(self.x), ax);
    ay = fmaf(eps1, bf2f_hi(self.x), ay);
    az = fmaf(eps1, bf2f_lo(self.y), az);
    aw = fmaf(eps1, bf2f_hi(self.y), aw);

    if (g == 0) {
        float4 v; v.x = ax; v.y = ay; v.z = az; v.w = aw;
        ((float4*)(agg + (size_t)n * 64))[sl] = v;
    }
}

// h_out[node][d] = relu(b[d] + sum_k agg[node][k] * W[k][d]) via MFMA.
// A-operand = Wt (hi/lo bf16), B-operand = agg rows (hi/lo bf16 in-register).
// D[m][n]: m = dim-within-mtile (= q*4+reg), n = node (= lane&15).
// One wave = 16 nodes. Zero LDS.
__global__ __launch_bounds__(256) void gemm_kernel(
        const float* __restrict__ agg, ushort_t* __restrict__ hout,
        const ushort_t* __restrict__ wt_hi, const ushort_t* __restrict__ wt_lo,
        const float* __restrict__ gin_b, int layer, int N) {
    int wave = threadIdx.x >> 6;
    int lane = threadIdx.x & 63;
    int tile = blockIdx.x * 4 + wave;
    if (tile * 16 >= N) return;
    int c = lane & 15;     // node within tile / n-index
    int q = lane >> 4;     // quad
    int node = tile * 16 + c;

    const ushort_t* Whi = wt_hi + layer * 4096;
    const ushort_t* Wlo = wt_lo + layer * 4096;
    const float*    bl  = gin_b + layer * 64;

    // B-frags: agg[node][k], k = kt*32 + q*8 + j
    v8bf bhi[2], blo2[2];
    #pragma unroll
    for (int kt = 0; kt < 2; ++kt) {
        const float* p = agg + (size_t)node * 64 + kt * 32 + q * 8;
        float4 f0 = ((const float4*)p)[0];
        float4 f1 = ((const float4*)p)[1];
        float xs[8] = {f0.x, f0.y, f0.z, f0.w, f1.x, f1.y, f1.z, f1.w};
        #pragma unroll
        for (int j = 0; j < 8; ++j) {
            __bf16 h = (__bf16)xs[j];
            bhi[kt][j] = h;
            blo2[kt][j] = (__bf16)(xs[j] - (float)h);
        }
    }

    #pragma unroll
    for (int mt = 0; mt < 4; ++mt) {
        v4f acc = {0.f, 0.f, 0.f, 0.f};
        #pragma unroll
        for (int kt = 0; kt < 2; ++kt) {
            int dim = mt * 16 + c;
            size_t off = (size_t)dim * 64 + kt * 32 + q * 8;
            v8bf ah = __builtin_bit_cast(v8bf, *(const uint4*)(Whi + off));
            v8bf al = __builtin_bit_cast(v8bf, *(const uint4*)(Wlo + off));
            acc = __builtin_amdgcn_mfma_f32_16x16x32_bf16(ah, bhi[kt],  acc, 0, 0, 0);
            acc = __builtin_amdgcn_mfma_f32_16x16x32_bf16(ah, blo2[kt], acc, 0, 0, 0);
            acc = __builtin_amdgcn_mfma_f32_16x16x32_bf16(al, bhi[kt],  acc, 0, 0, 0);
        }
        float4 bv = ((const float4*)(bl + mt * 16))[q];   // dims mt*16+q*4 .. +3
        float o0 = fmaxf(acc[0] + bv.x, 0.f);
        float o1 = fmaxf(acc[1] + bv.y, 0.f);
        float o2 = fmaxf(acc[2] + bv.z, 0.f);
        float o3 = fmaxf(acc[3] + bv.w, 0.f);
        uint2 pk;
        pk.x = (unsigned int)f2bf(o0) | ((unsigned int)f2bf(o1) << 16);
        pk.y = (unsigned int)f2bf(o2) | ((unsigned int)f2bf(o3) << 16);
        if (node < N)
            *(uint2*)(hout + (size_t)node * 64 + mt * 16 + q * 4) = pk;
    }
}

// 256 graphs x SPLIT splits; 192 threads (t = l*64+d); bf16 H, f32 accumulate.
__global__ __launch_bounds__(192) void readout_kernel(
        const ushort_t* __restrict__ H, const int* __restrict__ gids,
        float* __restrict__ g, int N) {
    int graph = blockIdx.x / SPLIT;
    int sp    = blockIdx.x % SPLIT;
    int lo = 0, hi = N;
    while (lo < hi) { int mid = (lo + hi) >> 1; if (gids[mid] < graph) lo = mid + 1; else hi = mid; }
    int start = lo;
    int lo2 = start, hi2 = N;
    while (lo2 < hi2) { int mid = (lo2 + hi2) >> 1; if (gids[mid] < graph + 1) lo2 = mid + 1; else hi2 = mid; }
    int end = lo2;
    int cnt = end - start;
    if (cnt <= 0) return;
    int per = (cnt + SPLIT - 1) / SPLIT;
    int cs = start + sp * per;
    int ce = min(cs + per, end);
    if (cs >= ce) return;

    int t = threadIdx.x;            // 0..191
    int l = t >> 6, d = t & 63;
    const ushort_t* Hl = H + (size_t)l * N * 64;
    float acc = 0.0f;
    for (int n = cs; n < ce; ++n)
        acc += bf2f_lo((unsigned int)Hl[(size_t)n * 64 + d]);
    atomicAdd(&g[graph * 192 + t], acc);
}

__global__ __launch_bounds__(192) void mlp_kernel(
        const float* __restrict__ g,
        const float* __restrict__ W1, const float* __restrict__ b1,
        const float* __restrict__ W2, const float* __restrict__ b2,
        float* __restrict__ out) {
    __shared__ float gr[192];
    __shared__ float hid[128];
    int graph = blockIdx.x;
    int t = threadIdx.x;
    gr[t] = g[graph * 192 + t];
    __syncthreads();
    if (t < 128) {
        float a = b1[t];
        for (int k = 0; k < 192; ++k) a = fmaf(gr[k], W1[k * 128 + t], a);
        hid[t] = fmaxf(a, 0.0f);
    }
    __syncthreads();
    if (t < 32) {
        float a = b2[t];
        for (int k = 0; k < 128; ++k) a = fmaf(hid[k], W2[k * 32 + t], a);
        out[graph * 32 + t] = a;
    }
}

extern "C" void kernel_launch(void* const* d_in, const int* in_sizes, int n_in,
                              void* d_out, int out_size, void* d_ws, size_t ws_size,
                              hipStream_t stream) {
    const float* x     = (const float*)d_in[0];
    const float* gin_W = (const float*)d_in[1];
    const float* gin_b = (const float*)d_in[2];
    const float* eps   = (const float*)d_in[3];
    const float* r_W1  = (const float*)d_in[4];
    const float* r_b1  = (const float*)d_in[5];
    const float* r_W2  = (const float*)d_in[6];
    const float* r_b2  = (const float*)d_in[7];
    const int*   src   = (const int*)d_in[8];
    const int*   dst   = (const int*)d_in[9];
    const int*   gids  = (const int*)d_in[10];

    int N = in_sizes[0] / 64;       // 100000
    int E = in_sizes[8];            // 1200000
    int B = out_size / 32;          // 256

    // workspace layout (4B words):
    //   deg[N] | cnt[N] | g[B*192]            <- zeroed
    //   offsets[N+1] | csr[E] | bsum | boff | pad
    //   xb[N*64 bf16] | H[3*N*64 bf16] | whi[3*4096 bf16] | wlo[...] | pad | agg[N*64 f32]
    int nb_scan = (N + 511) / 512;
    int* ws       = (int*)d_ws;
    int* deg      = ws;
    int* cnt      = ws + N;
    float* g      = (float*)(ws + 2 * (size_t)N);
    int* offsets  = ws + 2 * (size_t)N + B * 192;
    int* csr      = offsets + (N + 1);
    int* bsum     = csr + E;
    int* boff     = bsum + nb_scan;
    size_t w      = (size_t)(boff + nb_scan - ws);
    w = (w + 15) & ~(size_t)15;     // 64B align
    ushort_t* xb  = (ushort_t*)(ws + w);
    ushort_t* H   = xb + (size_t)N * 64;
    ushort_t* whi = H + 3 * (size_t)N * 64;
    ushort_t* wlo = whi + 3 * 4096;
    size_t w2     = ((size_t)((int*)(wlo + 3 * 4096) - ws) + 15) & ~(size_t)15;
    float* agg    = (float*)(ws + w2);

    size_t zero_bytes = (2 * (size_t)N + (size_t)B * 192) * sizeof(int);
    hipMemsetAsync(d_ws, 0, zero_bytes, stream);

    int eb = (E + 255) / 256;
    cast_kernel<<<(N * 64 / 4 + 255) / 256, 256, 0, stream>>>(x, xb, N * 64 / 4);
    prep_w_kernel<<<(3 * 4096 + 255) / 256, 256, 0, stream>>>(gin_W, whi, wlo, 3 * 4096);
    hist_kernel<<<eb, 256, 0, stream>>>(dst, deg, E);
    scan_part_kernel<<<nb_scan, 256, 0, stream>>>(deg, bsum, N);
    scan_mid_kernel<<<1, 256, 0, stream>>>(bsum, boff, nb_scan);
    scan_final_kernel<<<nb_scan, 256, 0, stream>>>(deg, boff, offsets, N, E);
    fill_kernel<<<eb, 256, 0, stream>>>(src, dst, offsets, cnt, csr, E);

    int nbk = (N + 3) / 4;                       // agg: wave per node, 4/block
    int gbk = ((N + 15) / 16 + 3) / 4;           // gemm: wave per 16 nodes, 4/block
    ushort_t* H0 = H;
    ushort_t* H1 = H + (size_t)N * 64;
    ushort_t* H2 = H + 2 * (size_t)N * 64;

    agg_kernel<<<nbk, 256, 0, stream>>>(xb, agg, offsets, csr, eps, 0, N);
    gemm_kernel<<<gbk, 256, 0, stream>>>(agg, H0, whi, wlo, gin_b, 0, N);
    agg_kernel<<<nbk, 256, 0, stream>>>(H0, agg, offsets, csr, eps, 1, N);
    gemm_kernel<<<gbk, 256, 0, stream>>>(agg, H1, whi, wlo, gin_b, 1, N);
    agg_kernel<<<nbk, 256, 0, stream>>>(H1, agg, offsets, csr, eps, 2, N);
    gemm_kernel<<<gbk, 256, 0, stream>>>(agg, H2, whi, wlo, gin_b, 2, N);

    readout_kernel<<<B * SPLIT, 192, 0, stream>>>(H, gids, g, N);
    mlp_kernel<<<B, 192, 0, stream>>>(g, r_W1, r_b1, r_W2, r_b2, (float*)d_out);
}

// Round 6
// 420.980 us; speedup vs baseline: 1.4461x; 1.0716x over previous
//
#include <hip/hip_runtime.h>

// GIN: 3 layers of {agg = scatter_sum(h[src] -> dst); h = relu(((1+eps)h + agg) @ W + b)}
// then per-graph segment-sum readout (graph_ids sorted) -> 2-layer MLP.
//
// R6: (a) XCD-local CSR build: hist/fill run as 8 dst-range passes keyed on
//     blockIdx%8 (~XCD round-robin). Kills the 85MB->4.8MB scatter write
//     amplification (R5: fill 72us, 17x writeback). hist stores per-edge rank
//     so fill is atomic-free. (b) agg: preload <=64 csr indices, shfl-broadcast,
//     unroll-4 gather -> ~4 gathers in flight (was 2, csr-latency-gated).
// R5: agg/MFMA-gemm split (DS pipe was saturated). R4: bf16 H. R3: parallel scan.

#define SPLIT 16
#define CHUNK 1024   // edges per (chunk,range) block in hist/fill

typedef unsigned short ushort_t;
typedef __bf16 v8bf __attribute__((ext_vector_type(8)));
typedef float v4f __attribute__((ext_vector_type(4)));

__device__ __forceinline__ ushort_t f2bf(float f) {
    unsigned int u = __float_as_uint(f);
    unsigned int r = (u + 0x7fffu + ((u >> 16) & 1u)) >> 16;   // RNE
    return (ushort_t)r;
}
__device__ __forceinline__ float bf2f_lo(unsigned int v) {
    return __uint_as_float(v << 16);
}
__device__ __forceinline__ float bf2f_hi(unsigned int v) {
    return __uint_as_float(v & 0xffff0000u);
}

__global__ void cast_kernel(const float* __restrict__ x, ushort_t* __restrict__ xb, int n4) {
    int i = blockIdx.x * blockDim.x + threadIdx.x;
    if (i < n4) {
        float4 v = ((const float4*)x)[i];
        uint2 p;
        p.x = (unsigned int)f2bf(v.x) | ((unsigned int)f2bf(v.y) << 16);
        p.y = (unsigned int)f2bf(v.z) | ((unsigned int)f2bf(v.w) << 16);
        ((uint2*)xb)[i] = p;
    }
}

// W[l][k][n] f32 -> Wt_hi/Wt_lo[l][n][k] bf16 (transposed, hi+lo split)
__global__ void prep_w_kernel(const float* __restrict__ W,
                              ushort_t* __restrict__ whi, ushort_t* __restrict__ wlo,
                              int total) {
    int i = blockIdx.x * blockDim.x + threadIdx.x;
    if (i >= total) return;
    int l = i >> 12, r = i & 4095;
    int n = r >> 6, k = r & 63;
    float w = W[l * 4096 + k * 64 + n];
    __bf16 h = (__bf16)w;
    float rem = w - (float)h;
    __bf16 lo = (__bf16)rem;
    whi[i] = __builtin_bit_cast(ushort_t, h);
    wlo[i] = __builtin_bit_cast(ushort_t, lo);
}

// 8-range histogram: block (chunk = b>>3, range = b&7). Only edges whose dst
// falls in this range are counted -> deg/rank lines touched by ~one XCD.
__global__ __launch_bounds__(256) void hist_kernel(const int* __restrict__ dst,
                                                   int* __restrict__ deg,
                                                   int* __restrict__ rank,
                                                   int E, int rsize) {
    int chunk = blockIdx.x >> 3;
    int range = blockIdx.x & 7;
    int rlo = range * rsize, rhi = rlo + rsize;
    int base = chunk * CHUNK;
    int end = min(base + CHUNK, E);
    for (int i = base + threadIdx.x; i < end; i += 256) {
        int d = dst[i];
        if (d >= rlo && d < rhi)
            rank[i] = atomicAdd(&deg[d], 1);
    }
}

// --- 3-phase parallel scan over deg[N] -> offsets[N+1] ---
__global__ __launch_bounds__(256) void scan_part_kernel(const int* __restrict__ deg,
                                                        int* __restrict__ bsum, int N) {
    __shared__ int sh[256];
    int t = threadIdx.x;
    int i = (blockIdx.x * 256 + t) * 2;
    int s = 0;
    if (i < N) s += deg[i];
    if (i + 1 < N) s += deg[i + 1];
    sh[t] = s;
    __syncthreads();
    for (int off = 128; off > 0; off >>= 1) {
        if (t < off) sh[t] += sh[t + off];
        __syncthreads();
    }
    if (t == 0) bsum[blockIdx.x] = sh[0];
}

__global__ __launch_bounds__(256) void scan_mid_kernel(const int* __restrict__ bsum,
                                                       int* __restrict__ boff, int nb) {
    __shared__ int sh[256];
    int t = threadIdx.x;
    int v = (t < nb) ? bsum[t] : 0;
    sh[t] = v;
    __syncthreads();
    for (int off = 1; off < 256; off <<= 1) {
        int u = (t >= off) ? sh[t - off] : 0;
        __syncthreads();
        sh[t] += u;
        __syncthreads();
    }
    if (t < nb) boff[t] = sh[t] - v;
}

__global__ __launch_bounds__(256) void scan_final_kernel(const int* __restrict__ deg,
                                                         const int* __restrict__ boff,
                                                         int* __restrict__ offsets,
                                                         int N, int E) {
    __shared__ int sh[256];
    int t = threadIdx.x;
    int i = (blockIdx.x * 256 + t) * 2;
    int d0 = (i < N) ? deg[i] : 0;
    int d1 = (i + 1 < N) ? deg[i + 1] : 0;
    int s = d0 + d1;
    sh[t] = s;
    __syncthreads();
    for (int off = 1; off < 256; off <<= 1) {
        int u = (t >= off) ? sh[t - off] : 0;
        __syncthreads();
        sh[t] += u;
        __syncthreads();
    }
    int pre = boff[blockIdx.x] + sh[t] - s;
    if (i < N) offsets[i] = pre;
    if (i + 1 < N) offsets[i + 1] = pre + d0;
    if (blockIdx.x == 0 && t == 0) offsets[N] = E;
}

// 8-range fill, atomic-free: csr[offsets[d] + rank[i]] = src[i].
// Each csr segment belongs to one dst-range -> written by ~one XCD.
__global__ __launch_bounds__(256) void fill_kernel(const int* __restrict__ src,
                                                   const int* __restrict__ dst,
                                                   const int* __restrict__ offsets,
                                                   const int* __restrict__ rank,
                                                   int* __restrict__ csr,
                                                   int E, int rsize) {
    int chunk = blockIdx.x >> 3;
    int range = blockIdx.x & 7;
    int rlo = range * rsize, rhi = rlo + rsize;
    int base = chunk * CHUNK;
    int end = min(base + CHUNK, E);
    for (int i = base + threadIdx.x; i < end; i += 256) {
        int d = dst[i];
        if (d >= rlo && d < rhi)
            csr[offsets[d] + rank[i]] = src[i];
    }
}

// One wave per node. Preload <=64 csr indices (one coalesced load), broadcast
// with shfl; unroll-4 gather loop -> ~4 independent 128B row loads in flight.
// lane = g*16+sl: group g handles edges j = g, g+4, ...; 16 lanes x uint2 = row.
__global__ __launch_bounds__(256) void agg_kernel(
        const ushort_t* __restrict__ hin, float* __restrict__ agg,
        const int* __restrict__ offsets, const int* __restrict__ csr,
        const float* __restrict__ eps_arr, int layer, int N) {
    int lane = threadIdx.x & 63;
    int wave = threadIdx.x >> 6;
    int n = blockIdx.x * 4 + wave;
    if (n >= N) return;
    float eps1 = 1.0f + eps_arr[layer];

    int g  = lane >> 4;    // edge group 0..3
    int sl = lane & 15;    // uint2 slot within row (dims 4sl..4sl+3)

    int e0 = offsets[n], e1 = offsets[n + 1];
    int deg = e1 - e0;
    int idx = (lane < deg) ? csr[e0 + lane] : 0;
    int dcap = min(deg, 64);

    float ax = 0.f, ay = 0.f, az = 0.f, aw = 0.f;
    #pragma unroll 4
    for (int j = g; j < dcap; j += 4) {
        int s = __shfl(idx, j, 64);
        uint2 v = ((const uint2*)(hin + (size_t)s * 64))[sl];
        ax += bf2f_lo(v.x); ay += bf2f_hi(v.x); az += bf2f_lo(v.y); aw += bf2f_hi(v.y);
    }
    // rare tail: deg > 64
    for (int e = e0 + 64 + g; e < e1; e += 4) {
        int s = csr[e];
        uint2 v = ((const uint2*)(hin + (size_t)s * 64))[sl];
        ax += bf2f_lo(v.x); ay += bf2f_hi(v.x); az += bf2f_lo(v.y); aw += bf2f_hi(v.y);
    }

    ax += __shfl_xor(ax, 16, 64); ax += __shfl_xor(ax, 32, 64);
    ay += __shfl_xor(ay, 16, 64); ay += __shfl_xor(ay, 32, 64);
    az += __shfl_xor(az, 16, 64); az += __shfl_xor(az, 32, 64);
    aw += __shfl_xor(aw, 16, 64); aw += __shfl_xor(aw, 32, 64);

    uint2 self = ((const uint2*)(hin + (size_t)n * 64))[sl];
    ax = fmaf(eps1, bf2f_lo(self.x), ax);
    ay = fmaf(eps1, bf2f_hi(self.x), ay);
    az = fmaf(eps1, bf2f_lo(self.y), az);
    aw = fmaf(eps1, bf2f_hi(self.y), aw);

    if (g == 0) {
        float4 v; v.x = ax; v.y = ay; v.z = az; v.w = aw;
        ((float4*)(agg + (size_t)n * 64))[sl] = v;
    }
}

// h_out[node][d] = relu(b[d] + sum_k agg[node][k] * W[k][d]) via MFMA.
// A = Wt (hi/lo bf16), B = agg rows (hi/lo bf16 in-register), 3-MFMA split product.
// One wave = 16 nodes. Zero LDS.
__global__ __launch_bounds__(256) void gemm_kernel(
        const float* __restrict__ agg, ushort_t* __restrict__ hout,
        const ushort_t* __restrict__ wt_hi, const ushort_t* __restrict__ wt_lo,
        const float* __restrict__ gin_b, int layer, int N) {
    int wave = threadIdx.x >> 6;
    int lane = threadIdx.x & 63;
    int tile = blockIdx.x * 4 + wave;
    if (tile * 16 >= N) return;
    int c = lane & 15;     // node within tile / n-index
    int q = lane >> 4;     // quad
    int node = tile * 16 + c;
    int lnode = min(node, N - 1);   // clamp loads; stores guarded below

    const ushort_t* Whi = wt_hi + layer * 4096;
    const ushort_t* Wlo = wt_lo + layer * 4096;
    const float*    bl  = gin_b + layer * 64;

    // B-frags: agg[node][k], k = kt*32 + q*8 + j
    v8bf bhi[2], blo2[2];
    #pragma unroll
    for (int kt = 0; kt < 2; ++kt) {
        const float* p = agg + (size_t)lnode * 64 + kt * 32 + q * 8;
        float4 f0 = ((const float4*)p)[0];
        float4 f1 = ((const float4*)p)[1];
        float xs[8] = {f0.x, f0.y, f0.z, f0.w, f1.x, f1.y, f1.z, f1.w};
        #pragma unroll
        for (int j = 0; j < 8; ++j) {
            __bf16 h = (__bf16)xs[j];
            bhi[kt][j] = h;
            blo2[kt][j] = (__bf16)(xs[j] - (float)h);
        }
    }

    #pragma unroll
    for (int mt = 0; mt < 4; ++mt) {
        v4f acc = {0.f, 0.f, 0.f, 0.f};
        #pragma unroll
        for (int kt = 0; kt < 2; ++kt) {
            int dim = mt * 16 + c;
            size_t off = (size_t)dim * 64 + kt * 32 + q * 8;
            v8bf ah = __builtin_bit_cast(v8bf, *(const uint4*)(Whi + off));
            v8bf al = __builtin_bit_cast(v8bf, *(const uint4*)(Wlo + off));
            acc = __builtin_amdgcn_mfma_f32_16x16x32_bf16(ah, bhi[kt],  acc, 0, 0, 0);
            acc = __builtin_amdgcn_mfma_f32_16x16x32_bf16(ah, blo2[kt], acc, 0, 0, 0);
            acc = __builtin_amdgcn_mfma_f32_16x16x32_bf16(al, bhi[kt],  acc, 0, 0, 0);
        }
        float4 bv = ((const float4*)(bl + mt * 16))[q];   // dims mt*16+q*4 .. +3
        float o0 = fmaxf(acc[0] + bv.x, 0.f);
        float o1 = fmaxf(acc[1] + bv.y, 0.f);
        float o2 = fmaxf(acc[2] + bv.z, 0.f);
        float o3 = fmaxf(acc[3] + bv.w, 0.f);
        uint2 pk;
        pk.x = (unsigned int)f2bf(o0) | ((unsigned int)f2bf(o1) << 16);
        pk.y = (unsigned int)f2bf(o2) | ((unsigned int)f2bf(o3) << 16);
        if (node < N)
            *(uint2*)(hout + (size_t)node * 64 + mt * 16 + q * 4) = pk;
    }
}

// 256 graphs x SPLIT splits; 192 threads (t = l*64+d); bf16 H, f32 accumulate.
__global__ __launch_bounds__(192) void readout_kernel(
        const ushort_t* __restrict__ H, const int* __restrict__ gids,
        float* __restrict__ g, int N) {
    int graph = blockIdx.x / SPLIT;
    int sp    = blockIdx.x % SPLIT;
    int lo = 0, hi = N;
    while (lo < hi) { int mid = (lo + hi) >> 1; if (gids[mid] < graph) lo = mid + 1; else hi = mid; }
    int start = lo;
    int lo2 = start, hi2 = N;
    while (lo2 < hi2) { int mid = (lo2 + hi2) >> 1; if (gids[mid] < graph + 1) lo2 = mid + 1; else hi2 = mid; }
    int end = lo2;
    int cnt = end - start;
    if (cnt <= 0) return;
    int per = (cnt + SPLIT - 1) / SPLIT;
    int cs = start + sp * per;
    int ce = min(cs + per, end);
    if (cs >= ce) return;

    int t = threadIdx.x;            // 0..191
    int l = t >> 6, d = t & 63;
    const ushort_t* Hl = H + (size_t)l * N * 64;
    float acc = 0.0f;
    for (int n = cs; n < ce; ++n)
        acc += bf2f_lo((unsigned int)Hl[(size_t)n * 64 + d]);
    atomicAdd(&g[graph * 192 + t], acc);
}

__global__ __launch_bounds__(192) void mlp_kernel(
        const float* __restrict__ g,
        const float* __restrict__ W1, const float* __restrict__ b1,
        const float* __restrict__ W2, const float* __restrict__ b2,
        float* __restrict__ out) {
    __shared__ float gr[192];
    __shared__ float hid[128];
    int graph = blockIdx.x;
    int t = threadIdx.x;
    gr[t] = g[graph * 192 + t];
    __syncthreads();
    if (t < 128) {
        float a = b1[t];
        for (int k = 0; k < 192; ++k) a = fmaf(gr[k], W1[k * 128 + t], a);
        hid[t] = fmaxf(a, 0.0f);
    }
    __syncthreads();
    if (t < 32) {
        float a = b2[t];
        for (int k = 0; k < 128; ++k) a = fmaf(hid[k], W2[k * 32 + t], a);
        out[graph * 32 + t] = a;
    }
}

extern "C" void kernel_launch(void* const* d_in, const int* in_sizes, int n_in,
                              void* d_out, int out_size, void* d_ws, size_t ws_size,
                              hipStream_t stream) {
    const float* x     = (const float*)d_in[0];
    const float* gin_W = (const float*)d_in[1];
    const float* gin_b = (const float*)d_in[2];
    const float* eps   = (const float*)d_in[3];
    const float* r_W1  = (const float*)d_in[4];
    const float* r_b1  = (const float*)d_in[5];
    const float* r_W2  = (const float*)d_in[6];
    const float* r_b2  = (const float*)d_in[7];
    const int*   src   = (const int*)d_in[8];
    const int*   dst   = (const int*)d_in[9];
    const int*   gids  = (const int*)d_in[10];

    int N = in_sizes[0] / 64;       // 100000
    int E = in_sizes[8];            // 1200000
    int B = out_size / 32;          // 256

    // workspace layout (4B words):
    //   deg[N] | g[B*192]                      <- zeroed
    //   offsets[N+1] | csr[E] | rank[E] | bsum | boff | pad
    //   xb[N*64 bf16] | H[3*N*64 bf16] | whi[3*4096] | wlo[3*4096] | pad | agg[N*64 f32]
    int nb_scan = (N + 511) / 512;
    int* ws       = (int*)d_ws;
    int* deg      = ws;
    float* g      = (float*)(ws + (size_t)N);
    int* offsets  = ws + (size_t)N + B * 192;
    int* csr      = offsets + (N + 1);
    int* rank     = csr + E;
    int* bsum     = rank + E;
    int* boff     = bsum + nb_scan;
    size_t w      = (size_t)(boff + nb_scan - ws);
    w = (w + 15) & ~(size_t)15;     // 64B align
    ushort_t* xb  = (ushort_t*)(ws + w);
    ushort_t* H   = xb + (size_t)N * 64;
    ushort_t* whi = H + 3 * (size_t)N * 64;
    ushort_t* wlo = whi + 3 * 4096;
    size_t w2     = ((size_t)((int*)(wlo + 3 * 4096) - ws) + 15) & ~(size_t)15;
    float* agg    = (float*)(ws + w2);

    size_t zero_bytes = ((size_t)N + (size_t)B * 192) * sizeof(int);
    hipMemsetAsync(d_ws, 0, zero_bytes, stream);

    int rsize = (N + 7) / 8;                 // dst-range size per pass
    int nchunks = (E + CHUNK - 1) / CHUNK;
    cast_kernel<<<(N * 64 / 4 + 255) / 256, 256, 0, stream>>>(x, xb, N * 64 / 4);
    prep_w_kernel<<<(3 * 4096 + 255) / 256, 256, 0, stream>>>(gin_W, whi, wlo, 3 * 4096);
    hist_kernel<<<nchunks * 8, 256, 0, stream>>>(dst, deg, rank, E, rsize);
    scan_part_kernel<<<nb_scan, 256, 0, stream>>>(deg, bsum, N);
    scan_mid_kernel<<<1, 256, 0, stream>>>(bsum, boff, nb_scan);
    scan_final_kernel<<<nb_scan, 256, 0, stream>>>(deg, boff, offsets, N, E);
    fill_kernel<<<nchunks * 8, 256, 0, stream>>>(src, dst, offsets, rank, csr, E, rsize);

    int nbk = (N + 3) / 4;                       // agg: wave per node, 4/block
    int gbk = ((N + 15) / 16 + 3) / 4;           // gemm: wave per 16 nodes, 4/block
    ushort_t* H0 = H;
    ushort_t* H1 = H + (size_t)N * 64;
    ushort_t* H2 = H + 2 * (size_t)N * 64;

    agg_kernel<<<nbk, 256, 0, stream>>>(xb, agg, offsets, csr, eps, 0, N);
    gemm_kernel<<<gbk, 256, 0, stream>>>(agg, H0, whi, wlo, gin_b, 0, N);
    agg_kernel<<<nbk, 256, 0, stream>>>(H0, agg, offsets, csr, eps, 1, N);
    gemm_kernel<<<gbk, 256, 0, stream>>>(agg, H1, whi, wlo, gin_b, 1, N);
    agg_kernel<<<nbk, 256, 0, stream>>>(H1, agg, offsets, csr, eps, 2, N);
    gemm_kernel<<<gbk, 256, 0, stream>>>(agg, H2, whi, wlo, gin_b, 2, N);

    readout_kernel<<<B * SPLIT, 192, 0, stream>>>(H, gids, g, N);
    mlp_kernel<<<B, 192, 0, stream>>>(g, r_W1, r_b1, r_W2, r_b2, (float*)d_out);
}

// Round 7
// 411.360 us; speedup vs baseline: 1.4799x; 1.0234x over previous
//
#include <hip/hip_runtime.h>

// GIN: 3 layers of {agg = scatter_sum(h[src] -> dst); h = relu(((1+eps)h + agg) @ W + b)}
// then per-graph segment-sum readout (graph_ids sorted) -> 2-layer MLP.
//
// R7: (a) hist back to single-pass atomic (rank written DENSE -> kills the
//     62MB/4.8MB rank write amplification that R6's range-split hist created;
//     cross-XCD deg atomics are cheap). fill stays 8-range atomic-free.
//     (b) H stored f16 (not bf16): same bytes, 8x less rounding error ->
//     restores absmax margin (was 1280/1495) against CSR-order perturbation.
// R6: XCD-local fill + agg shfl-preload. R5: agg/MFMA-gemm split. R3: par scan.

#define SPLIT 16
#define CHUNK 1024   // edges per (chunk,range) block in fill

typedef unsigned short ushort_t;
typedef __bf16 v8bf __attribute__((ext_vector_type(8)));
typedef float v4f __attribute__((ext_vector_type(4)));

__device__ __forceinline__ ushort_t f2bf(float f) {
    unsigned int u = __float_as_uint(f);
    unsigned int r = (u + 0x7fffu + ((u >> 16) & 1u)) >> 16;   // RNE
    return (ushort_t)r;
}
// f16 storage helpers
__device__ __forceinline__ float h2f_lo(unsigned int v) {
    return (float)__builtin_bit_cast(_Float16, (unsigned short)(v & 0xffffu));
}
__device__ __forceinline__ float h2f_hi(unsigned int v) {
    return (float)__builtin_bit_cast(_Float16, (unsigned short)(v >> 16));
}
__device__ __forceinline__ unsigned int f2h(float f) {
    return (unsigned int)__builtin_bit_cast(unsigned short, (_Float16)f);
}

__global__ void cast_kernel(const float* __restrict__ x, ushort_t* __restrict__ xh, int n4) {
    int i = blockIdx.x * blockDim.x + threadIdx.x;
    if (i < n4) {
        float4 v = ((const float4*)x)[i];
        uint2 p;
        p.x = f2h(v.x) | (f2h(v.y) << 16);
        p.y = f2h(v.z) | (f2h(v.w) << 16);
        ((uint2*)xh)[i] = p;
    }
}

// W[l][k][n] f32 -> Wt_hi/Wt_lo[l][n][k] bf16 (transposed, hi+lo split)
__global__ void prep_w_kernel(const float* __restrict__ W,
                              ushort_t* __restrict__ whi, ushort_t* __restrict__ wlo,
                              int total) {
    int i = blockIdx.x * blockDim.x + threadIdx.x;
    if (i >= total) return;
    int l = i >> 12, r = i & 4095;
    int n = r >> 6, k = r & 63;
    float w = W[l * 4096 + k * 64 + n];
    __bf16 h = (__bf16)w;
    float rem = w - (float)h;
    __bf16 lo = (__bf16)rem;
    whi[i] = __builtin_bit_cast(ushort_t, h);
    wlo[i] = __builtin_bit_cast(ushort_t, lo);
}

// Single-pass: deg count + per-edge rank (dense coalesced rank write).
__global__ void hist_kernel(const int* __restrict__ dst, int* __restrict__ deg,
                            int* __restrict__ rank, int E) {
    int i = blockIdx.x * blockDim.x + threadIdx.x;
    if (i < E) rank[i] = atomicAdd(&deg[dst[i]], 1);
}

// --- 3-phase parallel scan over deg[N] -> offsets[N+1] ---
__global__ __launch_bounds__(256) void scan_part_kernel(const int* __restrict__ deg,
                                                        int* __restrict__ bsum, int N) {
    __shared__ int sh[256];
    int t = threadIdx.x;
    int i = (blockIdx.x * 256 + t) * 2;
    int s = 0;
    if (i < N) s += deg[i];
    if (i + 1 < N) s += deg[i + 1];
    sh[t] = s;
    __syncthreads();
    for (int off = 128; off > 0; off >>= 1) {
        if (t < off) sh[t] += sh[t + off];
        __syncthreads();
    }
    if (t == 0) bsum[blockIdx.x] = sh[0];
}

__global__ __launch_bounds__(256) void scan_mid_kernel(const int* __restrict__ bsum,
                                                       int* __restrict__ boff, int nb) {
    __shared__ int sh[256];
    int t = threadIdx.x;
    int v = (t < nb) ? bsum[t] : 0;
    sh[t] = v;
    __syncthreads();
    for (int off = 1; off < 256; off <<= 1) {
        int u = (t >= off) ? sh[t - off] : 0;
        __syncthreads();
        sh[t] += u;
        __syncthreads();
    }
    if (t < nb) boff[t] = sh[t] - v;
}

__global__ __launch_bounds__(256) void scan_final_kernel(const int* __restrict__ deg,
                                                         const int* __restrict__ boff,
                                                         int* __restrict__ offsets,
                                                         int N, int E) {
    __shared__ int sh[256];
    int t = threadIdx.x;
    int i = (blockIdx.x * 256 + t) * 2;
    int d0 = (i < N) ? deg[i] : 0;
    int d1 = (i + 1 < N) ? deg[i + 1] : 0;
    int s = d0 + d1;
    sh[t] = s;
    __syncthreads();
    for (int off = 1; off < 256; off <<= 1) {
        int u = (t >= off) ? sh[t - off] : 0;
        __syncthreads();
        sh[t] += u;
        __syncthreads();
    }
    int pre = boff[blockIdx.x] + sh[t] - s;
    if (i < N) offsets[i] = pre;
    if (i + 1 < N) offsets[i + 1] = pre + d0;
    if (blockIdx.x == 0 && t == 0) offsets[N] = E;
}

// 8-range fill, atomic-free: csr[offsets[d] + rank[i]] = src[i].
// Each csr segment belongs to one dst-range -> written by ~one XCD.
__global__ __launch_bounds__(256) void fill_kernel(const int* __restrict__ src,
                                                   const int* __restrict__ dst,
                                                   const int* __restrict__ offsets,
                                                   const int* __restrict__ rank,
                                                   int* __restrict__ csr,
                                                   int E, int rsize) {
    int chunk = blockIdx.x >> 3;
    int range = blockIdx.x & 7;
    int rlo = range * rsize, rhi = rlo + rsize;
    int base = chunk * CHUNK;
    int end = min(base + CHUNK, E);
    for (int i = base + threadIdx.x; i < end; i += 256) {
        int d = dst[i];
        if (d >= rlo && d < rhi)
            csr[offsets[d] + rank[i]] = src[i];
    }
}

// One wave per node. Preload <=64 csr indices (one coalesced load), broadcast
// with shfl; unroll-4 gather loop -> ~4 independent 128B row loads in flight.
// lane = g*16+sl: group g handles edges j = g, g+4, ...; 16 lanes x uint2 = row.
__global__ __launch_bounds__(256) void agg_kernel(
        const ushort_t* __restrict__ hin, float* __restrict__ agg,
        const int* __restrict__ offsets, const int* __restrict__ csr,
        const float* __restrict__ eps_arr, int layer, int N) {
    int lane = threadIdx.x & 63;
    int wave = threadIdx.x >> 6;
    int n = blockIdx.x * 4 + wave;
    if (n >= N) return;
    float eps1 = 1.0f + eps_arr[layer];

    int g  = lane >> 4;    // edge group 0..3
    int sl = lane & 15;    // uint2 slot within row (dims 4sl..4sl+3)

    int e0 = offsets[n], e1 = offsets[n + 1];
    int deg = e1 - e0;
    int idx = (lane < deg) ? csr[e0 + lane] : 0;
    int dcap = min(deg, 64);

    float ax = 0.f, ay = 0.f, az = 0.f, aw = 0.f;
    #pragma unroll 4
    for (int j = g; j < dcap; j += 4) {
        int s = __shfl(idx, j, 64);
        uint2 v = ((const uint2*)(hin + (size_t)s * 64))[sl];
        ax += h2f_lo(v.x); ay += h2f_hi(v.x); az += h2f_lo(v.y); aw += h2f_hi(v.y);
    }
    // rare tail: deg > 64
    for (int e = e0 + 64 + g; e < e1; e += 4) {
        int s = csr[e];
        uint2 v = ((const uint2*)(hin + (size_t)s * 64))[sl];
        ax += h2f_lo(v.x); ay += h2f_hi(v.x); az += h2f_lo(v.y); aw += h2f_hi(v.y);
    }

    ax += __shfl_xor(ax, 16, 64); ax += __shfl_xor(ax, 32, 64);
    ay += __shfl_xor(ay, 16, 64); ay += __shfl_xor(ay, 32, 64);
    az += __shfl_xor(az, 16, 64); az += __shfl_xor(az, 32, 64);
    aw += __shfl_xor(aw, 16, 64); aw += __shfl_xor(aw, 32, 64);

    uint2 self = ((const uint2*)(hin + (size_t)n * 64))[sl];
    ax = fmaf(eps1, h2f_lo(self.x), ax);
    ay = fmaf(eps1, h2f_hi(self.x), ay);
    az = fmaf(eps1, h2f_lo(self.y), az);
    aw = fmaf(eps1, h2f_hi(self.y), aw);

    if (g == 0) {
        float4 v; v.x = ax; v.y = ay; v.z = az; v.w = aw;
        ((float4*)(agg + (size_t)n * 64))[sl] = v;
    }
}

// h_out[node][d] = relu(b[d] + sum_k agg[node][k] * W[k][d]) via MFMA.
// A = Wt (hi/lo bf16), B = agg rows (hi/lo bf16 in-register), 3-MFMA split product.
// One wave = 16 nodes. Zero LDS. H written f16.
__global__ __launch_bounds__(256) void gemm_kernel(
        const float* __restrict__ agg, ushort_t* __restrict__ hout,
        const ushort_t* __restrict__ wt_hi, const ushort_t* __restrict__ wt_lo,
        const float* __restrict__ gin_b, int layer, int N) {
    int wave = threadIdx.x >> 6;
    int lane = threadIdx.x & 63;
    int tile = blockIdx.x * 4 + wave;
    if (tile * 16 >= N) return;
    int c = lane & 15;     // node within tile / n-index
    int q = lane >> 4;     // quad
    int node = tile * 16 + c;
    int lnode = min(node, N - 1);   // clamp loads; stores guarded below

    const ushort_t* Whi = wt_hi + layer * 4096;
    const ushort_t* Wlo = wt_lo + layer * 4096;
    const float*    bl  = gin_b + layer * 64;

    // B-frags: agg[node][k], k = kt*32 + q*8 + j
    v8bf bhi[2], blo2[2];
    #pragma unroll
    for (int kt = 0; kt < 2; ++kt) {
        const float* p = agg + (size_t)lnode * 64 + kt * 32 + q * 8;
        float4 f0 = ((const float4*)p)[0];
        float4 f1 = ((const float4*)p)[1];
        float xs[8] = {f0.x, f0.y, f0.z, f0.w, f1.x, f1.y, f1.z, f1.w};
        #pragma unroll
        for (int j = 0; j < 8; ++j) {
            __bf16 h = (__bf16)xs[j];
            bhi[kt][j] = h;
            blo2[kt][j] = (__bf16)(xs[j] - (float)h);
        }
    }

    #pragma unroll
    for (int mt = 0; mt < 4; ++mt) {
        v4f acc = {0.f, 0.f, 0.f, 0.f};
        #pragma unroll
        for (int kt = 0; kt < 2; ++kt) {
            int dim = mt * 16 + c;
            size_t off = (size_t)dim * 64 + kt * 32 + q * 8;
            v8bf ah = __builtin_bit_cast(v8bf, *(const uint4*)(Whi + off));
            v8bf al = __builtin_bit_cast(v8bf, *(const uint4*)(Wlo + off));
            acc = __builtin_amdgcn_mfma_f32_16x16x32_bf16(ah, bhi[kt],  acc, 0, 0, 0);
            acc = __builtin_amdgcn_mfma_f32_16x16x32_bf16(ah, blo2[kt], acc, 0, 0, 0);
            acc = __builtin_amdgcn_mfma_f32_16x16x32_bf16(al, bhi[kt],  acc, 0, 0, 0);
        }
        float4 bv = ((const float4*)(bl + mt * 16))[q];   // dims mt*16+q*4 .. +3
        float o0 = fmaxf(acc[0] + bv.x, 0.f);
        float o1 = fmaxf(acc[1] + bv.y, 0.f);
        float o2 = fmaxf(acc[2] + bv.z, 0.f);
        float o3 = fmaxf(acc[3] + bv.w, 0.f);
        uint2 pk;
        pk.x = f2h(o0) | (f2h(o1) << 16);
        pk.y = f2h(o2) | (f2h(o3) << 16);
        if (node < N)
            *(uint2*)(hout + (size_t)node * 64 + mt * 16 + q * 4) = pk;
    }
}

// 256 graphs x SPLIT splits; 192 threads (t = l*64+d); f16 H, f32 accumulate.
__global__ __launch_bounds__(192) void readout_kernel(
        const ushort_t* __restrict__ H, const int* __restrict__ gids,
        float* __restrict__ g, int N) {
    int graph = blockIdx.x / SPLIT;
    int sp    = blockIdx.x % SPLIT;
    int lo = 0, hi = N;
    while (lo < hi) { int mid = (lo + hi) >> 1; if (gids[mid] < graph) lo = mid + 1; else hi = mid; }
    int start = lo;
    int lo2 = start, hi2 = N;
    while (lo2 < hi2) { int mid = (lo2 + hi2) >> 1; if (gids[mid] < graph + 1) lo2 = mid + 1; else hi2 = mid; }
    int end = lo2;
    int cnt = end - start;
    if (cnt <= 0) return;
    int per = (cnt + SPLIT - 1) / SPLIT;
    int cs = start + sp * per;
    int ce = min(cs + per, end);
    if (cs >= ce) return;

    int t = threadIdx.x;            // 0..191
    int l = t >> 6, d = t & 63;
    const ushort_t* Hl = H + (size_t)l * N * 64;
    float acc = 0.0f;
    for (int n = cs; n < ce; ++n)
        acc += (float)__builtin_bit_cast(_Float16, Hl[(size_t)n * 64 + d]);
    atomicAdd(&g[graph * 192 + t], acc);
}

__global__ __launch_bounds__(192) void mlp_kernel(
        const float* __restrict__ g,
        const float* __restrict__ W1, const float* __restrict__ b1,
        const float* __restrict__ W2, const float* __restrict__ b2,
        float* __restrict__ out) {
    __shared__ float gr[192];
    __shared__ float hid[128];
    int graph = blockIdx.x;
    int t = threadIdx.x;
    gr[t] = g[graph * 192 + t];
    __syncthreads();
    if (t < 128) {
        float a = b1[t];
        for (int k = 0; k < 192; ++k) a = fmaf(gr[k], W1[k * 128 + t], a);
        hid[t] = fmaxf(a, 0.0f);
    }
    __syncthreads();
    if (t < 32) {
        float a = b2[t];
        for (int k = 0; k < 128; ++k) a = fmaf(hid[k], W2[k * 32 + t], a);
        out[graph * 32 + t] = a;
    }
}

extern "C" void kernel_launch(void* const* d_in, const int* in_sizes, int n_in,
                              void* d_out, int out_size, void* d_ws, size_t ws_size,
                              hipStream_t stream) {
    const float* x     = (const float*)d_in[0];
    const float* gin_W = (const float*)d_in[1];
    const float* gin_b = (const float*)d_in[2];
    const float* eps   = (const float*)d_in[3];
    const float* r_W1  = (const float*)d_in[4];
    const float* r_b1  = (const float*)d_in[5];
    const float* r_W2  = (const float*)d_in[6];
    const float* r_b2  = (const float*)d_in[7];
    const int*   src   = (const int*)d_in[8];
    const int*   dst   = (const int*)d_in[9];
    const int*   gids  = (const int*)d_in[10];

    int N = in_sizes[0] / 64;       // 100000
    int E = in_sizes[8];            // 1200000
    int B = out_size / 32;          // 256

    // workspace layout (4B words):
    //   deg[N] | g[B*192]                      <- zeroed
    //   offsets[N+1] | csr[E] | rank[E] | bsum | boff | pad
    //   xh[N*64 f16] | H[3*N*64 f16] | whi[3*4096] | wlo[3*4096] | pad | agg[N*64 f32]
    int nb_scan = (N + 511) / 512;
    int* ws       = (int*)d_ws;
    int* deg      = ws;
    float* g      = (float*)(ws + (size_t)N);
    int* offsets  = ws + (size_t)N + B * 192;
    int* csr      = offsets + (N + 1);
    int* rank     = csr + E;
    int* bsum     = rank + E;
    int* boff     = bsum + nb_scan;
    size_t w      = (size_t)(boff + nb_scan - ws);
    w = (w + 15) & ~(size_t)15;     // 64B align
    ushort_t* xh  = (ushort_t*)(ws + w);
    ushort_t* H   = xh + (size_t)N * 64;
    ushort_t* whi = H + 3 * (size_t)N * 64;
    ushort_t* wlo = whi + 3 * 4096;
    size_t w2     = ((size_t)((int*)(wlo + 3 * 4096) - ws) + 15) & ~(size_t)15;
    float* agg    = (float*)(ws + w2);

    size_t zero_bytes = ((size_t)N + (size_t)B * 192) * sizeof(int);
    hipMemsetAsync(d_ws, 0, zero_bytes, stream);

    int rsize = (N + 7) / 8;                 // dst-range size per fill pass
    int nchunks = (E + CHUNK - 1) / CHUNK;
    int eb = (E + 255) / 256;
    cast_kernel<<<(N * 64 / 4 + 255) / 256, 256, 0, stream>>>(x, xh, N * 64 / 4);
    prep_w_kernel<<<(3 * 4096 + 255) / 256, 256, 0, stream>>>(gin_W, whi, wlo, 3 * 4096);
    hist_kernel<<<eb, 256, 0, stream>>>(dst, deg, rank, E);
    scan_part_kernel<<<nb_scan, 256, 0, stream>>>(deg, bsum, N);
    scan_mid_kernel<<<1, 256, 0, stream>>>(bsum, boff, nb_scan);
    scan_final_kernel<<<nb_scan, 256, 0, stream>>>(deg, boff, offsets, N, E);
    fill_kernel<<<nchunks * 8, 256, 0, stream>>>(src, dst, offsets, rank, csr, E, rsize);

    int nbk = (N + 3) / 4;                       // agg: wave per node, 4/block
    int gbk = ((N + 15) / 16 + 3) / 4;           // gemm: wave per 16 nodes, 4/block
    ushort_t* H0 = H;
    ushort_t* H1 = H + (size_t)N * 64;
    ushort_t* H2 = H + 2 * (size_t)N * 64;

    agg_kernel<<<nbk, 256, 0, stream>>>(xh, agg, offsets, csr, eps, 0, N);
    gemm_kernel<<<gbk, 256, 0, stream>>>(agg, H0, whi, wlo, gin_b, 0, N);
    agg_kernel<<<nbk, 256, 0, stream>>>(H0, agg, offsets, csr, eps, 1, N);
    gemm_kernel<<<gbk, 256, 0, stream>>>(agg, H1, whi, wlo, gin_b, 1, N);
    agg_kernel<<<nbk, 256, 0, stream>>>(H1, agg, offsets, csr, eps, 2, N);
    gemm_kernel<<<gbk, 256, 0, stream>>>(agg, H2, whi, wlo, gin_b, 2, N);

    readout_kernel<<<B * SPLIT, 192, 0, stream>>>(H, gids, g, N);
    mlp_kernel<<<B, 192, 0, stream>>>(g, r_W1, r_b1, r_W2, r_b2, (float*)d_out);
}